// Round 7
// baseline (247.411 us; speedup 1.0000x reference)
//
#include <hip/hip_runtime.h>

#define C_DIM 32
#define M_DIM 64
#define NG    8            // NGEN
#define TAB   (M_DIM * NG) // 512
#define ST    9            // padded stride for m-indexed LDS tables
#define BST   520          // padded c-stride (floats) for staged B
#define NPB   512          // nodes per consumer block
#define READY 0x5A17C0DEu

// ---------------------------------------------------------------------------
// Single fused dispatch.
// Block 0 (producer): computes the 3x512 (m,g) tables from LDS-staged B,
//   publishes them in ws, then device-scope release-stores READY.
// Blocks 1..ncb (consumers): stage x/batch for 512 nodes while producer runs,
//   acquire-spin on the flag, then (A) coalesced hv/hi writes, (B) walk every
//   graph that STARTS in their range to its end (sequential fp32 sum,
//   deterministic, one writer per out_like cell), zero-filling empty graphs.
// Flag self-resets via a ticket counter -> no state visible across calls.
// Grid (587 blocks) < full co-residency capacity -> spin-wait cannot deadlock.
// ---------------------------------------------------------------------------
__global__ void __launch_bounds__(256)
cgmm_fused(const float* __restrict__ B, const float* __restrict__ Pi,
           const int* __restrict__ x, const int* __restrict__ batch,
           float* __restrict__ tab, unsigned int* __restrict__ flag,
           unsigned int* __restrict__ cc,
           float* __restrict__ out_like, float* __restrict__ out_hv,
           float* __restrict__ out_hi, int N, int G, int ncb) {
    const int tid = threadIdx.x;

    if (blockIdx.x == 0) {
        // ---------------- producer: tables ----------------
        __shared__ float Bs[C_DIM * BST];     // padded c-stride, conflict-free
        __shared__ float Pis[C_DIM * NG];
        __shared__ float lsePi_s[NG];
        __shared__ float K_s[C_DIM * NG];     // Pi - lseB - lsePi

        const float4* B4 = (const float4*)B;
        float4* Bs4 = (float4*)Bs;
        #pragma unroll
        for (int i = tid; i < (C_DIM * M_DIM * NG) / 4; i += 256)
            Bs4[(i >> 7) * (BST / 4) + (i & 127)] = B4[i];
        if (tid < C_DIM * NG / 4) ((float4*)Pis)[tid] = ((const float4*)Pi)[tid];
        __syncthreads();

        if (tid < NG) {
            float mx = -1e30f;
            #pragma unroll
            for (int c = 0; c < C_DIM; ++c) mx = fmaxf(mx, Pis[c * NG + tid]);
            float s = 0.f;
            #pragma unroll
            for (int c = 0; c < C_DIM; ++c) s += expf(Pis[c * NG + tid] - mx);
            lsePi_s[tid] = logf(s) + mx;
        }
        __syncthreads();

        {   // 256 threads = (c,g): lseB over m -> K
            const int g = tid & 7;
            const float* bp = Bs + (tid >> 3) * BST + g;
            float mx = -1e30f;
            #pragma unroll
            for (int m = 0; m < M_DIM; ++m) mx = fmaxf(mx, bp[m * NG]);
            float s = 0.f;
            #pragma unroll
            for (int m = 0; m < M_DIM; ++m) s += expf(bp[m * NG] - mx);
            K_s[tid] = Pis[tid] - (logf(s) + mx) - lsePi_s[g];
        }
        __syncthreads();

        {   // 256 threads, 2 m-values each
            const int q = tid >> 3, g = tid & 7;
            #pragma unroll
            for (int h = 0; h < 2; ++h) {
                const int m = q + 32 * h;
                float L[C_DIM];
                float best = -1e30f; int bidx = 0;
                #pragma unroll
                for (int c = 0; c < C_DIM; ++c) {
                    float v = Bs[c * BST + m * NG + g] + K_s[c * NG + g];
                    L[c] = v;
                    if (v > best) { best = v; bidx = c; }   // strict >, first max
                }
                float se = 0.f, la = 0.f;
                #pragma unroll
                for (int c = 0; c < C_DIM; ++c) {
                    float e = expf(L[c] - best);
                    se += e; la += e * L[c];
                }
                const int idx = m * NG + g;
                tab[idx]           = la / se;     // like
                tab[TAB + idx]     = 1.f / se;    // hval = max posterior
                tab[2 * TAB + idx] = (float)bidx; // hidx
            }
        }
        __syncthreads();   // all tab stores drained (vmcnt(0) before barrier)
        if (tid == 0) {
            __hip_atomic_store(cc, 0u, __ATOMIC_RELAXED, __HIP_MEMORY_SCOPE_AGENT);
            __threadfence();  // device-scope release of tab stores
            __hip_atomic_store(flag, READY, __ATOMIC_RELEASE, __HIP_MEMORY_SCOPE_AGENT);
        }
        return;
    }

    // ---------------- consumers ----------------
    __shared__ float like_s[M_DIM * ST];
    __shared__ float hval_s[M_DIM * ST];
    __shared__ float hidx_s[M_DIM * ST];
    __shared__ int   xs_s[NPB];
    __shared__ int   bs_s[NPB + 1];   // bs_s[0] = batch[base-1] (or -1)

    const int base   = (int)(blockIdx.x - 1) * NPB;
    const int nvalid = min(NPB, N - base);

    // stage x/batch BEFORE waiting (overlaps producer latency)
    for (int i = tid; i < nvalid; i += 256) {
        xs_s[i]     = x[base + i];
        bs_s[i + 1] = batch[base + i];
    }
    if (tid == 0) bs_s[0] = (base > 0) ? batch[base - 1] : -1;

    // acquire-spin: each wave independently acquires table visibility
    while (__hip_atomic_load(flag, __ATOMIC_ACQUIRE, __HIP_MEMORY_SCOPE_AGENT) != READY)
        __builtin_amdgcn_s_sleep(2);

    // ticket: last consumer to pass the wait resets the flag for next replay
    if (tid == 0) {
        if (atomicAdd(cc, 1u) == (unsigned)(ncb - 1))
            __hip_atomic_store(flag, 0u, __ATOMIC_RELAXED, __HIP_MEMORY_SCOPE_AGENT);
    }

    for (int i = tid; i < TAB; i += 256) {
        const int p = (i >> 3) * ST + (i & 7);
        like_s[p] = tab[i];
        hval_s[p] = tab[TAB + i];
        hidx_s[p] = tab[2 * TAB + i];
    }
    __syncthreads();

    const int grp = tid >> 3;   // 0..31
    const int g   = tid & 7;    // 0..7

    // phase A: hv/hi writes, 256B contiguous per wave per step
    #pragma unroll
    for (int k = 0; k < NPB / 32; ++k) {
        const int i = k * 32 + grp;
        if (i >= nvalid) break;
        const int p = xs_s[i] * ST + g;
        out_hv[(size_t)(base + i) * NG + g] = hval_s[p];
        out_hi[(size_t)(base + i) * NG + g] = hidx_s[p];
    }

    // phase B: graphs starting in this block; sequential deterministic sum,
    // walking across the block end via (L2-hot) global reads if needed.
    for (int i = grp; i < nvalid; i += 32) {
        const int j  = bs_s[i + 1];
        const int jp = bs_s[i];
        if (j == jp) continue;            // not a graph start
        float acc = 0.f;
        int n = i;
        while (true) {
            const int xm = (n < nvalid) ? xs_s[n] : x[base + n];
            acc += like_s[xm * ST + g];
            ++n;
            if (base + n >= N) break;
            const int bn = (n < nvalid) ? bs_s[n + 1] : batch[base + n];
            if (bn != j) break;
        }
        out_like[(size_t)j * NG + g] = acc;
        for (int e = jp + 1; e < j; ++e)              // empty graphs
            out_like[(size_t)e * NG + g] = 0.f;
    }
    if (base + nvalid == N) {                          // tail empty graphs
        const int jl = bs_s[nvalid];
        for (int e = jl + 1 + grp; e < G; e += 32)
            out_like[(size_t)e * NG + g] = 0.f;
    }
}

extern "C" void kernel_launch(void* const* d_in, const int* in_sizes, int n_in,
                              void* d_out, int out_size, void* d_ws, size_t ws_size,
                              hipStream_t stream) {
    const float* B     = (const float*)d_in[0];   // (C, M, NG)
    const float* Pi    = (const float*)d_in[1];   // (C, NG)
    const int*   x     = (const int*)d_in[2];     // (N,)
    const int*   batch = (const int*)d_in[3];     // (N,) sorted
    const int N = in_sizes[2];
    const int G = (out_size - 2 * N * NG) / NG;   // out = [G*NG | N*NG | N*NG]

    float*        tab  = (float*)d_ws;                       // 1536 floats
    unsigned int* flag = (unsigned int*)((char*)d_ws + 8192);
    unsigned int* cc   = (unsigned int*)((char*)d_ws + 8196);

    float* out_like = (float*)d_out;
    float* out_hv   = out_like + (size_t)G * NG;
    float* out_hi   = out_hv + (size_t)N * NG;

    const int ncb = (N + NPB - 1) / NPB;          // consumer blocks

    cgmm_fused<<<ncb + 1, 256, 0, stream>>>(B, Pi, x, batch, tab, flag, cc,
                                            out_like, out_hv, out_hi, N, G, ncb);
}

// Round 8
// 56.601 us; speedup vs baseline: 4.3712x; 4.3712x over previous
//
#include <hip/hip_runtime.h>

#define C_DIM 32
#define M_DIM 64
#define NG    8            // NGEN
#define TAB   (M_DIM * NG) // 512
#define ST    9            // padded stride for m-indexed LDS tables
#define BST   520          // padded c-stride (floats) for staged B
#define NPB   256          // nodes per D2 block (== threads)

// ---------------------------------------------------------------------------
// D1: ONE block, 512 threads = (m,g) pairs. LDS-staged B (padded, conflict-
// free), shift-free lse (inputs bounded +-5 -> no overflow), fast intrinsics.
//   tab[0..511]=like, tab[512..1023]=hval, tab[1024..1535]=hidx
// ---------------------------------------------------------------------------
__global__ void __launch_bounds__(512)
cgmm_tables(const float* __restrict__ B, const float* __restrict__ Pi,
            float* __restrict__ tab) {
    __shared__ float Bs[C_DIM * BST];
    __shared__ float Pis[C_DIM * NG];
    __shared__ float lsePi_s[NG];
    __shared__ float K_s[C_DIM * NG];   // Pi - lseB - lsePi

    const int tid = threadIdx.x;
    {   // coalesced float4 staging into padded layout
        const float4* B4 = (const float4*)B;
        float4* Bs4 = (float4*)Bs;
        #pragma unroll
        for (int i = tid; i < (C_DIM * M_DIM * NG) / 4; i += 512)
            Bs4[(i >> 7) * (BST / 4) + (i & 127)] = B4[i];
        if (tid < C_DIM * NG / 4) ((float4*)Pis)[tid] = ((const float4*)Pi)[tid];
    }
    __syncthreads();

    if (tid < NG) {   // shift-free lsePi (|Pi|<=5)
        float s = 0.f;
        #pragma unroll
        for (int c = 0; c < C_DIM; ++c) s += __expf(Pis[c * NG + tid]);
        lsePi_s[tid] = __logf(s);
    }
    __syncthreads();

    if (tid < C_DIM * NG) {   // lanes=(c,g): Bs bank = lane%32, conflict-free
        const int g = tid & 7;
        const float* bp = Bs + (tid >> 3) * BST + g;
        float s = 0.f;
        #pragma unroll
        for (int m = 0; m < M_DIM; ++m) s += __expf(bp[m * NG]);
        K_s[tid] = Pis[tid] - __logf(s) - lsePi_s[g];
    }
    __syncthreads();

    {   // 512 threads = (m,g)
        const int m = tid >> 3, g = tid & 7;
        float L[C_DIM];
        float best = -1e30f; int bidx = 0;
        #pragma unroll
        for (int c = 0; c < C_DIM; ++c) {
            float v = Bs[c * BST + m * NG + g] + K_s[c * NG + g];
            L[c] = v;
            if (v > best) { best = v; bidx = c; }   // strict >, first max
        }
        float se = 0.f, la = 0.f;
        #pragma unroll
        for (int c = 0; c < C_DIM; ++c) {
            float e = __expf(L[c] - best);
            se += e; la += e * L[c];
        }
        tab[tid]           = la / se;     // like
        tab[TAB + tid]     = 1.f / se;    // hval = max posterior
        tab[2 * TAB + tid] = (float)bidx; // hidx
    }
}

// ---------------------------------------------------------------------------
// D2: node-parallel, 256 nodes per 256-thread block, no starts[] needed.
//  A: hv/hi as float4 (lane<->float4-slot: fully contiguous 1KB/wave stores)
//  B: graphs STARTING in this range are walked to their end (sequential fp32
//     sum, deterministic single writer per out_like cell); empty graphs and
//     the tail are zero-filled by their unique detector.
// ---------------------------------------------------------------------------
__global__ void __launch_bounds__(256)
cgmm_nodes(const int* __restrict__ x, const int* __restrict__ batch,
           const float* __restrict__ tab,
           float* __restrict__ out_like, float* __restrict__ out_hv,
           float* __restrict__ out_hi, int N, int G) {
    __shared__ float like_s[M_DIM * ST];
    __shared__ float hval_s[M_DIM * ST];
    __shared__ float hidx_s[M_DIM * ST];
    __shared__ int   xs_s[NPB];
    __shared__ int   bs_s[NPB + 1];   // bs_s[0] = batch[base-1] (or -1)

    const int tid  = threadIdx.x;
    const int base = blockIdx.x * NPB;
    const int nvalid = min(NPB, N - base);

    for (int i = tid; i < TAB; i += 256) {
        const int p = (i >> 3) * ST + (i & 7);
        like_s[p] = tab[i];
        hval_s[p] = tab[TAB + i];
        hidx_s[p] = tab[2 * TAB + i];
    }
    if (tid < nvalid) {
        xs_s[tid]     = x[base + tid];
        bs_s[tid + 1] = batch[base + tid];
    }
    if (tid == 0) bs_s[0] = (base > 0) ? batch[base - 1] : -1;
    __syncthreads();

    // phase A: float4 hv/hi stores, contiguous per wave instruction
    float4* hv4 = (float4*)out_hv;
    float4* hi4 = (float4*)out_hi;
    #pragma unroll
    for (int k = 0; k < 2; ++k) {
        const int f = k * 256 + tid;       // float4 slot within block
        const int i = f >> 1;              // node
        const int h = (f & 1) * 4;         // half (gens 0-3 / 4-7)
        if (i < nvalid) {
            const int p = xs_s[i] * ST + h;
            float4 v, w;
            v.x = hval_s[p];     v.y = hval_s[p + 1];
            v.z = hval_s[p + 2]; v.w = hval_s[p + 3];
            w.x = hidx_s[p];     w.y = hidx_s[p + 1];
            w.z = hidx_s[p + 2]; w.w = hidx_s[p + 3];
            hv4[(size_t)base * 2 + f] = v;
            hi4[(size_t)base * 2 + f] = w;
        }
    }

    // phase B: walk graphs starting here; fill empty graphs; tail fill
    const int grp = tid >> 3;   // 0..31
    const int g   = tid & 7;    // 0..7
    for (int i = grp; i < nvalid; i += 32) {
        const int j  = bs_s[i + 1];
        const int jp = bs_s[i];
        if (j == jp) continue;            // not a graph start
        float acc = 0.f;
        int n = i;
        while (true) {
            const int xm = (n < nvalid) ? xs_s[n] : x[base + n];
            acc += like_s[xm * ST + g];
            ++n;
            if (base + n >= N) break;
            const int bn = (n < nvalid) ? bs_s[n + 1] : batch[base + n];
            if (bn != j) break;
        }
        out_like[(size_t)j * NG + g] = acc;
        for (int e = jp + 1; e < j; ++e)              // empty graphs
            out_like[(size_t)e * NG + g] = 0.f;
    }
    if (base + nvalid == N) {                          // tail empty graphs
        const int jl = bs_s[nvalid];
        for (int e = jl + 1 + grp; e < G; e += 32)
            out_like[(size_t)e * NG + g] = 0.f;
    }
}

extern "C" void kernel_launch(void* const* d_in, const int* in_sizes, int n_in,
                              void* d_out, int out_size, void* d_ws, size_t ws_size,
                              hipStream_t stream) {
    const float* B     = (const float*)d_in[0];   // (C, M, NG)
    const float* Pi    = (const float*)d_in[1];   // (C, NG)
    const int*   x     = (const int*)d_in[2];     // (N,)
    const int*   batch = (const int*)d_in[3];     // (N,) sorted
    const int N = in_sizes[2];
    const int G = (out_size - 2 * N * NG) / NG;   // out = [G*NG | N*NG | N*NG]

    float* tab = (float*)d_ws;                    // 1536 floats

    float* out_like = (float*)d_out;
    float* out_hv   = out_like + (size_t)G * NG;
    float* out_hi   = out_hv + (size_t)N * NG;

    cgmm_tables<<<1, 512, 0, stream>>>(B, Pi, tab);
    cgmm_nodes<<<(N + NPB - 1) / NPB, 256, 0, stream>>>(x, batch, tab, out_like,
                                                        out_hv, out_hi, N, G);
}

// Round 9
// 20.027 us; speedup vs baseline: 12.3539x; 2.8262x over previous
//
#include <hip/hip_runtime.h>

#define C_DIM 32
#define M_DIM 64
#define NG    8            // NGEN
#define TAB   (M_DIM * NG) // 512
#define ST    9            // padded stride for m-indexed LDS tables
#define SPB   1024         // nodes per starts-scan block (256 threads)

// ws layout (bytes): tab @0 (6KB) | Sexp @8192 (1KB) | lsePi @9216 | starts @16384

// ---------------------------------------------------------------------------
// D0: blocks 0..31: Sexp[c,g] = sum_m exp(B[c,m,g]) (serial m-ascending, same
// rounding as prior passing rounds). Block 32: lsePi[g]. Blocks 33..: starts
// scan. All independent -> one dispatch, fully parallel B read.
// ---------------------------------------------------------------------------
__global__ void __launch_bounds__(256)
cgmm_partials(const float* __restrict__ B, const float* __restrict__ Pi,
              const int* __restrict__ batch,
              float* __restrict__ Sexp, float* __restrict__ lsePi,
              int* __restrict__ starts, int N, int G) {
    const int tid = threadIdx.x;
    const int bid = blockIdx.x;

    if (bid < C_DIM) {
        // one c-row of B: 512 floats, coalesced stage then 8 serial g-sums
        __shared__ float row_s[M_DIM * NG];
        const float* row = B + bid * (M_DIM * NG);
        row_s[tid]       = row[tid];
        row_s[tid + 256] = row[tid + 256];
        __syncthreads();
        if (tid < NG) {
            float s = 0.f;
            #pragma unroll
            for (int m = 0; m < M_DIM; ++m) s += __expf(row_s[m * NG + tid]);
            Sexp[bid * NG + tid] = s;
        }
        return;
    }
    if (bid == C_DIM) {
        __shared__ float pi_s[C_DIM * NG];
        pi_s[tid] = Pi[tid];
        __syncthreads();
        if (tid < NG) {
            float s = 0.f;
            #pragma unroll
            for (int c = 0; c < C_DIM; ++c) s += __expf(pi_s[c * NG + tid]);
            lsePi[tid] = __logf(s);
        }
        return;
    }

    // ---- starts-scan blocks ----
    const int base = (bid - C_DIM - 1) * SPB;
    for (int i = tid; i < SPB; i += 256) {
        const int n = base + i;
        if (n >= N) break;
        const int bn = batch[n];
        if (n == 0) {
            for (int j = 0; j <= bn; ++j) starts[j] = 0;
        } else {
            const int bp = batch[n - 1];
            for (int j = bp + 1; j <= bn; ++j) starts[j] = n;  // empty if equal
        }
        if (n == N - 1) {
            for (int j = bn + 1; j <= G; ++j) starts[j] = N;
        }
    }
}

// ---------------------------------------------------------------------------
// D1: ONE block, 512 threads = (m,g). B now L2/L3-hot; per c-iteration a wave
// reads 256B contiguous (lanes = consecutive m*8+g). K from Sexp/lsePi.
// ---------------------------------------------------------------------------
__global__ void __launch_bounds__(512)
cgmm_tables(const float* __restrict__ B, const float* __restrict__ Pi,
            const float* __restrict__ Sexp, const float* __restrict__ lsePi,
            float* __restrict__ tab) {
    __shared__ float K_s[C_DIM * NG];
    const int tid = threadIdx.x;
    if (tid < C_DIM * NG)
        K_s[tid] = Pi[tid] - __logf(Sexp[tid]) - lsePi[tid & 7];
    __syncthreads();

    const int g = tid & 7;
    float L[C_DIM];
    float best = -1e30f; int bidx = 0;
    #pragma unroll
    for (int c = 0; c < C_DIM; ++c) {
        float v = B[c * (M_DIM * NG) + tid] + K_s[c * NG + g];
        L[c] = v;
        if (v > best) { best = v; bidx = c; }   // strict >, first max
    }
    float se = 0.f, la = 0.f;
    #pragma unroll
    for (int c = 0; c < C_DIM; ++c) {
        float e = __expf(L[c] - best);
        se += e; la += e * L[c];
    }
    tab[tid]           = la / se;     // like
    tab[TAB + tid]     = 1.f / se;    // hval = max posterior
    tab[2 * TAB + tid] = (float)bidx; // hidx
}

// ---------------------------------------------------------------------------
// D2 (R5-proven): one 64-lane wave per graph (4 per block). starts[] lookup,
// padded tables in LDS, single pass: conflict-light gathers, 256B/wave
// coalesced hv/hi stores, deterministic shuffle-reduced likelihood.
// ---------------------------------------------------------------------------
__global__ void __launch_bounds__(256)
cgmm_write(const int* __restrict__ x, const int* __restrict__ starts,
           const float* __restrict__ tab,
           float* __restrict__ out_like, float* __restrict__ out_hv,
           float* __restrict__ out_hi, int G) {
    __shared__ float like_s[M_DIM * ST];
    __shared__ float hval_s[M_DIM * ST];
    __shared__ float hidx_s[M_DIM * ST];
    const int tid = threadIdx.x;
    for (int i = tid; i < TAB; i += 256) {
        const int p = (i >> 3) * ST + (i & 7);
        like_s[p] = tab[i];
        hval_s[p] = tab[TAB + i];
        hidx_s[p] = tab[2 * TAB + i];
    }
    __syncthreads();

    const int j = blockIdx.x * 4 + (tid >> 6);
    if (j >= G) return;
    const int start = starts[j];
    const int end   = starts[j + 1];

    const int slot = (tid >> 3) & 7;
    const int g    = tid & 7;

    float acc = 0.f;
    for (int n = start + slot; n < end; n += 8) {
        const int xm = x[n];                 // 8 lanes/addr broadcast
        const int p  = xm * ST + g;
        acc += like_s[p];
        out_hv[(size_t)n * NG + g] = hval_s[p];   // wave: 256B contiguous
        out_hi[(size_t)n * NG + g] = hidx_s[p];
    }
    acc += __shfl_xor(acc, 8);
    acc += __shfl_xor(acc, 16);
    acc += __shfl_xor(acc, 32);
    if ((tid & 63) < NG) out_like[(size_t)j * NG + g] = acc;
}

extern "C" void kernel_launch(void* const* d_in, const int* in_sizes, int n_in,
                              void* d_out, int out_size, void* d_ws, size_t ws_size,
                              hipStream_t stream) {
    const float* B     = (const float*)d_in[0];   // (C, M, NG)
    const float* Pi    = (const float*)d_in[1];   // (C, NG)
    const int*   x     = (const int*)d_in[2];     // (N,)
    const int*   batch = (const int*)d_in[3];     // (N,) sorted
    const int N = in_sizes[2];
    const int G = (out_size - 2 * N * NG) / NG;   // out = [G*NG | N*NG | N*NG]

    float* tab    = (float*)d_ws;                        // 1536 floats
    float* Sexp   = (float*)((char*)d_ws + 8192);        // 256 floats
    float* lsePi  = (float*)((char*)d_ws + 9216);        // 8 floats
    int*   starts = (int*)((char*)d_ws + 16384);         // G+1 ints

    float* out_like = (float*)d_out;
    float* out_hv   = out_like + (size_t)G * NG;
    float* out_hi   = out_hv + (size_t)N * NG;

    const int nsb = (N + SPB - 1) / SPB;                 // starts-scan blocks

    cgmm_partials<<<C_DIM + 1 + nsb, 256, 0, stream>>>(B, Pi, batch, Sexp,
                                                       lsePi, starts, N, G);
    cgmm_tables<<<1, 512, 0, stream>>>(B, Pi, Sexp, lsePi, tab);
    cgmm_write<<<(G + 3) / 4, 256, 0, stream>>>(x, starts, tab, out_like,
                                                out_hv, out_hi, G);
}

// Round 11
// 19.742 us; speedup vs baseline: 12.5324x; 1.0144x over previous
//
#include <hip/hip_runtime.h>

#define C_DIM 32
#define M_DIM 64
#define NG    8            // NGEN
#define TAB   (M_DIM * NG) // 512
#define ST    9            // padded stride for m-indexed LDS tables
#define SPB   1024         // nodes per starts-scan block (256 threads)

// ws layout (bytes): tab @0 (6KB) | Sexp @8192 (1KB) | lsePi @9216 | starts @16384

// ---------------------------------------------------------------------------
// D0 (R9-proven): blocks 0..31: Sexp[c,g] = sum_m exp(B[c,m,g]). Block 32:
// lsePi[g]. Blocks 33..: starts scan. All independent, fully parallel.
// ---------------------------------------------------------------------------
__global__ void __launch_bounds__(256)
cgmm_partials(const float* __restrict__ B, const float* __restrict__ Pi,
              const int* __restrict__ batch,
              float* __restrict__ Sexp, float* __restrict__ lsePi,
              int* __restrict__ starts, int N, int G) {
    const int tid = threadIdx.x;
    const int bid = blockIdx.x;

    if (bid < C_DIM) {
        __shared__ float row_s[M_DIM * NG];
        const float* row = B + bid * (M_DIM * NG);
        row_s[tid]       = row[tid];
        row_s[tid + 256] = row[tid + 256];
        __syncthreads();
        if (tid < NG) {
            float s = 0.f;
            #pragma unroll
            for (int m = 0; m < M_DIM; ++m) s += __expf(row_s[m * NG + tid]);
            Sexp[bid * NG + tid] = s;
        }
        return;
    }
    if (bid == C_DIM) {
        __shared__ float pi_s[C_DIM * NG];
        pi_s[tid] = Pi[tid];
        __syncthreads();
        if (tid < NG) {
            float s = 0.f;
            #pragma unroll
            for (int c = 0; c < C_DIM; ++c) s += __expf(pi_s[c * NG + tid]);
            lsePi[tid] = __logf(s);
        }
        return;
    }

    const int base = (bid - C_DIM - 1) * SPB;
    for (int i = tid; i < SPB; i += 256) {
        const int n = base + i;
        if (n >= N) break;
        const int bn = batch[n];
        if (n == 0) {
            for (int j = 0; j <= bn; ++j) starts[j] = 0;
        } else {
            const int bp = batch[n - 1];
            for (int j = bp + 1; j <= bn; ++j) starts[j] = n;  // empty if equal
        }
        if (n == N - 1) {
            for (int j = bn + 1; j <= G; ++j) starts[j] = N;
        }
    }
}

// ---------------------------------------------------------------------------
// D1 (R9-proven): ONE block, 512 threads = (m,g). B is L2/L3-hot; per
// c-iteration a wave reads 256B contiguous. K from Sexp/lsePi.
// ---------------------------------------------------------------------------
__global__ void __launch_bounds__(512)
cgmm_tables(const float* __restrict__ B, const float* __restrict__ Pi,
            const float* __restrict__ Sexp, const float* __restrict__ lsePi,
            float* __restrict__ tab) {
    __shared__ float K_s[C_DIM * NG];
    const int tid = threadIdx.x;
    if (tid < C_DIM * NG)
        K_s[tid] = Pi[tid] - __logf(Sexp[tid]) - lsePi[tid & 7];
    __syncthreads();

    const int g = tid & 7;
    float L[C_DIM];
    float best = -1e30f; int bidx = 0;
    #pragma unroll
    for (int c = 0; c < C_DIM; ++c) {
        float v = B[c * (M_DIM * NG) + tid] + K_s[c * NG + g];
        L[c] = v;
        if (v > best) { best = v; bidx = c; }   // strict >, first max
    }
    float se = 0.f, la = 0.f;
    #pragma unroll
    for (int c = 0; c < C_DIM; ++c) {
        float e = __expf(L[c] - best);
        se += e; la += e * L[c];
    }
    tab[tid]           = la / se;     // like
    tab[TAB + tid]     = 1.f / se;    // hval = max posterior
    tab[2 * TAB + tid] = (float)bidx; // hidx
}

// ---------------------------------------------------------------------------
// D2: 512 threads = 8 waves, one graph per wave. Per 64-node chunk: ONE
// coalesced x load (registers, distributed via shfl), float4 hv/hi stores,
// deterministic shuffle-reduced like sum.
// FIX vs R10: every __shfl is executed by ALL 64 lanes (hoisted out of the
// divergent predicate) — ds_bpermute from an exec-masked-off source lane
// returns undefined data, which corrupted tail chunks.
// ---------------------------------------------------------------------------
__global__ void __launch_bounds__(512)
cgmm_write(const int* __restrict__ x, const int* __restrict__ starts,
           const float* __restrict__ tab,
           float* __restrict__ out_like, float* __restrict__ out_hv,
           float* __restrict__ out_hi, int G) {
    __shared__ float like_s[M_DIM * ST];
    __shared__ float hval_s[M_DIM * ST];
    __shared__ float hidx_s[M_DIM * ST];
    const int tid = threadIdx.x;
    for (int i = tid; i < TAB; i += 512) {
        const int p = (i >> 3) * ST + (i & 7);
        like_s[p] = tab[i];
        hval_s[p] = tab[TAB + i];
        hidx_s[p] = tab[2 * TAB + i];
    }
    __syncthreads();

    const int j = blockIdx.x * 8 + (tid >> 6);
    if (j >= G) return;                   // wave-uniform
    const int start = starts[j];
    const int end   = starts[j + 1];

    const int lane = tid & 63;
    const int slot = lane >> 3;   // 0..7
    const int g    = lane & 7;    // 0..7

    float4* hv4 = (float4*)out_hv;
    float4* hi4 = (float4*)out_hi;

    float acc = 0.f;
    for (int cb = start; cb < end; cb += 64) {     // wave-uniform loop
        const int cnt = end - cb;
        const int xv  = (cb + lane < end) ? x[cb + lane] : 0;

        // hv/hi: 2 float4 store instrs per array cover 64 nodes
        #pragma unroll
        for (int s = 0; s < 2; ++s) {
            const int f    = s * 64 + lane;   // float4 slot within chunk
            const int node = f >> 1;
            const int h    = (f & 1) * 4;
            const int xm   = __shfl(xv, node);     // ALL lanes participate
            if (node < cnt) {
                const int p = xm * ST + h;
                float4 v, w;
                v.x = hval_s[p];     v.y = hval_s[p + 1];
                v.z = hval_s[p + 2]; v.w = hval_s[p + 3];
                w.x = hidx_s[p];     w.y = hidx_s[p + 1];
                w.z = hidx_s[p + 2]; w.w = hidx_s[p + 3];
                hv4[(size_t)cb * 2 + f] = v;
                hi4[(size_t)cb * 2 + f] = w;
            }
        }
        // like partials: same (slot,g) ownership/order as proven rounds
        #pragma unroll
        for (int t = 0; t < 8; ++t) {
            const int node = slot + 8 * t;
            const int xm   = __shfl(xv, node);     // ALL lanes participate
            if (node < cnt) acc += like_s[xm * ST + g];
        }
    }
    acc += __shfl_xor(acc, 8);
    acc += __shfl_xor(acc, 16);
    acc += __shfl_xor(acc, 32);
    if (lane < NG) out_like[(size_t)j * NG + g] = acc;   // 0 for empty graphs
}

extern "C" void kernel_launch(void* const* d_in, const int* in_sizes, int n_in,
                              void* d_out, int out_size, void* d_ws, size_t ws_size,
                              hipStream_t stream) {
    const float* B     = (const float*)d_in[0];   // (C, M, NG)
    const float* Pi    = (const float*)d_in[1];   // (C, NG)
    const int*   x     = (const int*)d_in[2];     // (N,)
    const int*   batch = (const int*)d_in[3];     // (N,) sorted
    const int N = in_sizes[2];
    const int G = (out_size - 2 * N * NG) / NG;   // out = [G*NG | N*NG | N*NG]

    float* tab    = (float*)d_ws;                        // 1536 floats
    float* Sexp   = (float*)((char*)d_ws + 8192);        // 256 floats
    float* lsePi  = (float*)((char*)d_ws + 9216);        // 8 floats
    int*   starts = (int*)((char*)d_ws + 16384);         // G+1 ints

    float* out_like = (float*)d_out;
    float* out_hv   = out_like + (size_t)G * NG;
    float* out_hi   = out_hv + (size_t)N * NG;

    const int nsb = (N + SPB - 1) / SPB;                 // starts-scan blocks

    cgmm_partials<<<C_DIM + 1 + nsb, 256, 0, stream>>>(B, Pi, batch, Sexp,
                                                       lsePi, starts, N, G);
    cgmm_tables<<<1, 512, 0, stream>>>(B, Pi, Sexp, lsePi, tab);
    cgmm_write<<<(G + 7) / 8, 512, 0, stream>>>(x, starts, tab, out_like,
                                                out_hv, out_hi, G);
}

// Round 12
// 17.989 us; speedup vs baseline: 13.7537x; 1.0975x over previous
//
#include <hip/hip_runtime.h>

#define C_DIM 32
#define M_DIM 64
#define NG    8            // NGEN
#define TAB   (M_DIM * NG) // 512
#define ST    9            // padded stride for m-indexed LDS tables
#define BST   520          // padded c-stride (floats) for staged B
#define SPB   1024         // nodes per starts-scan block (256 threads)
#define NTB   8            // table blocks (8 m-values each)

// ws layout (bytes): tab @0 (6KB) | starts @16384 (G+1 ints)

// ---------------------------------------------------------------------------
// D0 (fused, no internal dependency):
//   blocks 0..7   : table blocks. Each stages all of B (64KB, coalesced,
//                   padded stride -> <=2-way LDS banking), computes its own
//                   lsePi + Sexp (m-ascending serial order, bit-identical to
//                   prior passing rounds), then emits 64 table entries
//                   (m in [bid*8, bid*8+8), g=0..7).
//   blocks 8..    : starts-scan blocks (boundary fill, total work = G).
// ---------------------------------------------------------------------------
__global__ void __launch_bounds__(256)
cgmm_prep(const float* __restrict__ B, const float* __restrict__ Pi,
          const int* __restrict__ batch,
          float* __restrict__ tab, int* __restrict__ starts,
          int N, int G) {
    const int tid = threadIdx.x;
    const int bid = blockIdx.x;

    if (bid < NTB) {
        // ---- table block ----
        __shared__ float Bs[C_DIM * BST];     // ~66.5 KB, padded c-stride
        __shared__ float Pis[C_DIM * NG];
        __shared__ float lsePi_s[NG];
        __shared__ float K_s[C_DIM * NG];     // Pi - lseB - lsePi

        const float4* B4 = (const float4*)B;
        float4* Bs4 = (float4*)Bs;
        #pragma unroll
        for (int i = tid; i < (C_DIM * M_DIM * NG) / 4; i += 256)
            Bs4[(i >> 7) * (BST / 4) + (i & 127)] = B4[i];
        if (tid < C_DIM * NG / 4) ((float4*)Pis)[tid] = ((const float4*)Pi)[tid];
        __syncthreads();

        if (tid < NG) {   // shift-free lsePi (|Pi|<=5)
            float s = 0.f;
            #pragma unroll
            for (int c = 0; c < C_DIM; ++c) s += __expf(Pis[c * NG + tid]);
            lsePi_s[tid] = __logf(s);
        }
        __syncthreads();

        {   // thread <-> (c,g): Sexp (serial m-ascending) -> K
            const int g = tid & 7;
            const float* bp = Bs + (tid >> 3) * BST + g;
            float s = 0.f;
            #pragma unroll
            for (int m = 0; m < M_DIM; ++m) s += __expf(bp[m * NG]);
            K_s[tid] = Pis[tid] - __logf(s) - lsePi_s[g];
        }
        __syncthreads();

        if (tid < 64) {   // 64 entries: m = bid*8 + (tid>>3), g = tid&7
            const int m = bid * NTB + (tid >> 3);
            const int g = tid & 7;
            float L[C_DIM];
            float best = -1e30f; int bidx = 0;
            #pragma unroll
            for (int c = 0; c < C_DIM; ++c) {
                float v = Bs[c * BST + m * NG + g] + K_s[c * NG + g];
                L[c] = v;
                if (v > best) { best = v; bidx = c; }   // strict >, first max
            }
            float se = 0.f, la = 0.f;
            #pragma unroll
            for (int c = 0; c < C_DIM; ++c) {
                float e = __expf(L[c] - best);
                se += e; la += e * L[c];
            }
            const int idx = m * NG + g;
            tab[idx]           = la / se;     // like
            tab[TAB + idx]     = 1.f / se;    // hval = max posterior
            tab[2 * TAB + idx] = (float)bidx; // hidx
        }
        return;
    }

    // ---- starts-scan blocks ----
    const int base = (bid - NTB) * SPB;
    for (int i = tid; i < SPB; i += 256) {
        const int n = base + i;
        if (n >= N) break;
        const int bn = batch[n];
        if (n == 0) {
            for (int j = 0; j <= bn; ++j) starts[j] = 0;
        } else {
            const int bp = batch[n - 1];
            for (int j = bp + 1; j <= bn; ++j) starts[j] = n;  // empty if equal
        }
        if (n == N - 1) {
            for (int j = bn + 1; j <= G; ++j) starts[j] = N;
        }
    }
}

// ---------------------------------------------------------------------------
// D2 (R11-proven): 512 threads = 8 waves, one graph per wave. Per 64-node
// chunk: ONE coalesced x load (registers, distributed via shfl — all lanes
// participate in every shfl), float4 hv/hi stores, deterministic
// shuffle-reduced like sum.
// ---------------------------------------------------------------------------
__global__ void __launch_bounds__(512)
cgmm_write(const int* __restrict__ x, const int* __restrict__ starts,
           const float* __restrict__ tab,
           float* __restrict__ out_like, float* __restrict__ out_hv,
           float* __restrict__ out_hi, int G) {
    __shared__ float like_s[M_DIM * ST];
    __shared__ float hval_s[M_DIM * ST];
    __shared__ float hidx_s[M_DIM * ST];
    const int tid = threadIdx.x;
    for (int i = tid; i < TAB; i += 512) {
        const int p = (i >> 3) * ST + (i & 7);
        like_s[p] = tab[i];
        hval_s[p] = tab[TAB + i];
        hidx_s[p] = tab[2 * TAB + i];
    }
    __syncthreads();

    const int j = blockIdx.x * 8 + (tid >> 6);
    if (j >= G) return;                   // wave-uniform
    const int start = starts[j];
    const int end   = starts[j + 1];

    const int lane = tid & 63;
    const int slot = lane >> 3;   // 0..7
    const int g    = lane & 7;    // 0..7

    float4* hv4 = (float4*)out_hv;
    float4* hi4 = (float4*)out_hi;

    float acc = 0.f;
    for (int cb = start; cb < end; cb += 64) {     // wave-uniform loop
        const int cnt = end - cb;
        const int xv  = (cb + lane < end) ? x[cb + lane] : 0;

        #pragma unroll
        for (int s = 0; s < 2; ++s) {
            const int f    = s * 64 + lane;   // float4 slot within chunk
            const int node = f >> 1;
            const int h    = (f & 1) * 4;
            const int xm   = __shfl(xv, node);     // ALL lanes participate
            if (node < cnt) {
                const int p = xm * ST + h;
                float4 v, w;
                v.x = hval_s[p];     v.y = hval_s[p + 1];
                v.z = hval_s[p + 2]; v.w = hval_s[p + 3];
                w.x = hidx_s[p];     w.y = hidx_s[p + 1];
                w.z = hidx_s[p + 2]; w.w = hidx_s[p + 3];
                hv4[(size_t)cb * 2 + f] = v;
                hi4[(size_t)cb * 2 + f] = w;
            }
        }
        #pragma unroll
        for (int t = 0; t < 8; ++t) {
            const int node = slot + 8 * t;
            const int xm   = __shfl(xv, node);     // ALL lanes participate
            if (node < cnt) acc += like_s[xm * ST + g];
        }
    }
    acc += __shfl_xor(acc, 8);
    acc += __shfl_xor(acc, 16);
    acc += __shfl_xor(acc, 32);
    if (lane < NG) out_like[(size_t)j * NG + g] = acc;   // 0 for empty graphs
}

extern "C" void kernel_launch(void* const* d_in, const int* in_sizes, int n_in,
                              void* d_out, int out_size, void* d_ws, size_t ws_size,
                              hipStream_t stream) {
    const float* B     = (const float*)d_in[0];   // (C, M, NG)
    const float* Pi    = (const float*)d_in[1];   // (C, NG)
    const int*   x     = (const int*)d_in[2];     // (N,)
    const int*   batch = (const int*)d_in[3];     // (N,) sorted
    const int N = in_sizes[2];
    const int G = (out_size - 2 * N * NG) / NG;   // out = [G*NG | N*NG | N*NG]

    float* tab    = (float*)d_ws;                        // 1536 floats
    int*   starts = (int*)((char*)d_ws + 16384);         // G+1 ints

    float* out_like = (float*)d_out;
    float* out_hv   = out_like + (size_t)G * NG;
    float* out_hi   = out_hv + (size_t)N * NG;

    const int nsb = (N + SPB - 1) / SPB;                 // starts-scan blocks

    cgmm_prep<<<NTB + nsb, 256, 0, stream>>>(B, Pi, batch, tab, starts, N, G);
    cgmm_write<<<(G + 7) / 8, 512, 0, stream>>>(x, starts, tab, out_like,
                                                out_hv, out_hi, G);
}